// Round 21
// baseline (1382.227 us; speedup 1.0000x reference)
//
#include <hip/hip_runtime.h>
#include <math.h>

#define SEQT 1024
#define NTOK 2048
#define HIDN 512
#define NHD 8
#define HDIM 64
#define KTSN 4

__device__ __forceinline__ float wred(float v) {
#pragma unroll
  for (int off = 32; off; off >>= 1) v += __shfl_xor(v, off, 64);
  return v;
}

// rotation-allreduce within rows of 16 via DPP (VALU-speed)
template <int CTRL>
__device__ __forceinline__ float rra(float v) {
  return v + __int_as_float(__builtin_amdgcn_update_dpp(
                 0, __float_as_int(v), CTRL, 0xf, 0xf, true));
}
__device__ __forceinline__ float rlane(float v, int l) {
  return __int_as_float(__builtin_amdgcn_readlane(__float_as_int(v), l));
}
// full-wave sum: 4 DPP row_rors (row sums) + 4 readlanes + adds.
__device__ __forceinline__ float wsum64_fast(float v) {
  v = rra<0x121>(v);  // row_ror:1
  v = rra<0x122>(v);  // row_ror:2
  v = rra<0x124>(v);  // row_ror:4
  v = rra<0x128>(v);  // row_ror:8  -> each lane has its 16-lane row sum
  return (rlane(v, 0) + rlane(v, 16)) + (rlane(v, 32) + rlane(v, 48));
}

// ---------------- K1: input RMSNorm (one block per row) ----------------
__global__ __launch_bounds__(256) void k_rmsnorm_in(
    const float* __restrict__ x, const float* __restrict__ w, float* __restrict__ xn) {
  int m = blockIdx.x;
  int tid = threadIdx.x;
  const float* row = x + (size_t)m * HIDN;
  float2 v = *(const float2*)(row + tid * 2);
  float ss = wred(v.x * v.x + v.y * v.y);
  __shared__ float red[4];
  int lane = tid & 63, wv = tid >> 6;
  if (lane == 0) red[wv] = ss;
  __syncthreads();
  float tot = red[0] + red[1] + red[2] + red[3];
  float inv = rsqrtf(tot * (1.0f / HIDN) + 1e-5f);
  float2 wv2 = *(const float2*)(w + tid * 2);
  float2 o;
  o.x = v.x * inv * wv2.x;
  o.y = v.y * inv * wv2.y;
  *(float2*)(xn + (size_t)m * HIDN + tid * 2) = o;
}

// ---------------- K2a: fused QKV GEMM ----------------
__global__ __launch_bounds__(256) void k_gemm_qkv(
    const float* __restrict__ A, const float* __restrict__ Bq,
    const float* __restrict__ Bk, const float* __restrict__ Bv,
    float* __restrict__ Cq, float* __restrict__ Ck, float* __restrict__ Cv) {
  __shared__ __align__(16) float As[32][68];
  __shared__ __align__(16) float Bs0[32][68];
  __shared__ __align__(16) float Bs1[32][68];
  __shared__ __align__(16) float Bs2[32][68];
  int tid = threadIdx.x;
  int m0 = blockIdx.x * 64, n0 = blockIdx.y * 64;
  int tm = tid >> 4, tn = tid & 15;
  float aq[4][4] = {}, ak[4][4] = {}, av4[4][4] = {};
  int rr = tid >> 2, cc = (tid & 3) * 8;
  for (int k0 = 0; k0 < HIDN; k0 += 32) {
    const float* s0 = A + (size_t)(m0 + rr) * HIDN + k0 + cc;
    float4 a0 = *(const float4*)s0;
    float4 a1 = *(const float4*)(s0 + 4);
    As[cc + 0][rr] = a0.x; As[cc + 1][rr] = a0.y; As[cc + 2][rr] = a0.z; As[cc + 3][rr] = a0.w;
    As[cc + 4][rr] = a1.x; As[cc + 5][rr] = a1.y; As[cc + 6][rr] = a1.z; As[cc + 7][rr] = a1.w;
    size_t boff = (size_t)(n0 + rr) * HIDN + k0 + cc;
    float4 b0 = *(const float4*)(Bq + boff);
    float4 b1 = *(const float4*)(Bq + boff + 4);
    Bs0[cc + 0][rr] = b0.x; Bs0[cc + 1][rr] = b0.y; Bs0[cc + 2][rr] = b0.z; Bs0[cc + 3][rr] = b0.w;
    Bs0[cc + 4][rr] = b1.x; Bs0[cc + 5][rr] = b1.y; Bs0[cc + 6][rr] = b1.z; Bs0[cc + 7][rr] = b1.w;
    b0 = *(const float4*)(Bk + boff);
    b1 = *(const float4*)(Bk + boff + 4);
    Bs1[cc + 0][rr] = b0.x; Bs1[cc + 1][rr] = b0.y; Bs1[cc + 2][rr] = b0.z; Bs1[cc + 3][rr] = b0.w;
    Bs1[cc + 4][rr] = b1.x; Bs1[cc + 5][rr] = b1.y; Bs1[cc + 6][rr] = b1.z; Bs1[cc + 7][rr] = b1.w;
    b0 = *(const float4*)(Bv + boff);
    b1 = *(const float4*)(Bv + boff + 4);
    Bs2[cc + 0][rr] = b0.x; Bs2[cc + 1][rr] = b0.y; Bs2[cc + 2][rr] = b0.z; Bs2[cc + 3][rr] = b0.w;
    Bs2[cc + 4][rr] = b1.x; Bs2[cc + 5][rr] = b1.y; Bs2[cc + 6][rr] = b1.z; Bs2[cc + 7][rr] = b1.w;
    __syncthreads();
#pragma unroll
    for (int kk = 0; kk < 32; ++kk) {
      float4 a4 = *(const float4*)&As[kk][tm * 4];
      float4 q4 = *(const float4*)&Bs0[kk][tn * 4];
      float4 k4 = *(const float4*)&Bs1[kk][tn * 4];
      float4 v4 = *(const float4*)&Bs2[kk][tn * 4];
      float aa[4] = {a4.x, a4.y, a4.z, a4.w};
      float qq[4] = {q4.x, q4.y, q4.z, q4.w};
      float kk_[4] = {k4.x, k4.y, k4.z, k4.w};
      float vv[4] = {v4.x, v4.y, v4.z, v4.w};
#pragma unroll
      for (int i = 0; i < 4; ++i)
#pragma unroll
        for (int j = 0; j < 4; ++j) {
          aq[i][j] = fmaf(aa[i], qq[j], aq[i][j]);
          ak[i][j] = fmaf(aa[i], kk_[j], ak[i][j]);
          av4[i][j] = fmaf(aa[i], vv[j], av4[i][j]);
        }
    }
    __syncthreads();
  }
#pragma unroll
  for (int i = 0; i < 4; ++i) {
    size_t mr = (size_t)(m0 + tm * 4 + i) * HIDN;
#pragma unroll
    for (int j = 0; j < 4; ++j) {
      int nc = n0 + tn * 4 + j;
      Cq[mr + nc] = aq[i][j];
      Ck[mr + nc] = ak[i][j];
      Cv[mr + nc] = av4[i][j];
    }
  }
}

// ---------------- K2b: fused alpha/mix GEMM ----------------
__global__ __launch_bounds__(256) void k_gemm_am(
    const float* __restrict__ A, const float* __restrict__ Ba,
    const float* __restrict__ Bm, float* __restrict__ Ca, float* __restrict__ Cm) {
  __shared__ __align__(16) float As[32][68];
  __shared__ __align__(16) float Bs[32][68];
  int tid = threadIdx.x;
  int m0 = blockIdx.x * 64;
  int tm = tid >> 4, tn = tid & 15;
  float acc[4][4] = {};
  int rr = tid >> 2, cc = (tid & 3) * 8;
  for (int k0 = 0; k0 < HIDN; k0 += 32) {
    const float* s0 = A + (size_t)(m0 + rr) * HIDN + k0 + cc;
    float4 a0 = *(const float4*)s0;
    float4 a1 = *(const float4*)(s0 + 4);
    As[cc + 0][rr] = a0.x; As[cc + 1][rr] = a0.y; As[cc + 2][rr] = a0.z; As[cc + 3][rr] = a0.w;
    As[cc + 4][rr] = a1.x; As[cc + 5][rr] = a1.y; As[cc + 6][rr] = a1.z; As[cc + 7][rr] = a1.w;
    const float* s1 = ((rr < 32) ? (Ba + (size_t)rr * HIDN) : (Bm + (size_t)(rr - 32) * HIDN)) + k0 + cc;
    float4 b0 = *(const float4*)s1;
    float4 b1 = *(const float4*)(s1 + 4);
    Bs[cc + 0][rr] = b0.x; Bs[cc + 1][rr] = b0.y; Bs[cc + 2][rr] = b0.z; Bs[cc + 3][rr] = b0.w;
    Bs[cc + 4][rr] = b1.x; Bs[cc + 5][rr] = b1.y; Bs[cc + 6][rr] = b1.z; Bs[cc + 7][rr] = b1.w;
    __syncthreads();
#pragma unroll
    for (int kk = 0; kk < 32; ++kk) {
      float4 a4 = *(const float4*)&As[kk][tm * 4];
      float4 b4 = *(const float4*)&Bs[kk][tn * 4];
      float aa[4] = {a4.x, a4.y, a4.z, a4.w};
      float bb[4] = {b4.x, b4.y, b4.z, b4.w};
#pragma unroll
      for (int i = 0; i < 4; ++i)
#pragma unroll
        for (int j = 0; j < 4; ++j) acc[i][j] = fmaf(aa[i], bb[j], acc[i][j]);
    }
    __syncthreads();
  }
#pragma unroll
  for (int i = 0; i < 4; ++i) {
    int mr = m0 + tm * 4 + i;
#pragma unroll
    for (int j = 0; j < 4; ++j) {
      int nc = tn * 4 + j;
      if (nc < 32)
        Ca[(size_t)mr * 32 + nc] = acc[i][j];
      else
        Cm[(size_t)mr * 32 + nc - 32] = acc[i][j];
    }
  }
}

// ---------------- K3a: rope cos/sin table [t][j] ----------------
__global__ __launch_bounds__(256) void k_rope_table(float2* __restrict__ tab) {
  int idx = blockIdx.x * 256 + threadIdx.x;  // 1024*32
  int t = idx >> 5, j = idx & 31;
  float invf = (float)exp2(-(double)j * (13.287712379549449 / 32.0));  // 10000^(-j/32)
  float ang = (float)t * invf;                                         // fp32, matches ref
  double s, c;
  sincos((double)ang, &s, &c);
  tab[idx] = make_float2((float)c, (float)s);
}

// ---------------- K3b: rope(q,k), rmsnorm(k,v), alpha, mix; transpose; qkd/kvq scalars ----------------
__global__ __launch_bounds__(256) void k_postproc(
    const float* __restrict__ q_in, const float* __restrict__ k_in, const float* __restrict__ v_in,
    const float* __restrict__ a_pre, const float* __restrict__ m_pre,
    const float* __restrict__ ab, const float* __restrict__ mb,
    const float* __restrict__ kn_w, const float* __restrict__ vn_w,
    const float2* __restrict__ tab,
    float* __restrict__ qh, float* __restrict__ kh, float* __restrict__ vh,
    float* __restrict__ av, float* __restrict__ mv,
    float* __restrict__ qkd, float* __restrict__ kvq) {
  int wid = blockIdx.x * 4 + (threadIdx.x >> 6);  // one wave per (b,t,h)
  int lane = threadIdx.x & 63;
  int b = wid >> 13;
  int rem = wid & 8191;
  int t = rem >> 3;
  int h = rem & 7;
  size_t src = (size_t)(b * SEQT + t) * HIDN + h * HDIM + lane;
  float qv = q_in[src], kv = k_in[src], vv = v_in[src];
  float2 cs = tab[t * 32 + (lane & 31)];
  float qpart = __shfl_xor(qv, 32, 64);
  float kpart = __shfl_xor(kv, 32, 64);
  float qr = (lane < 32) ? (qv * cs.x - qpart * cs.y) : (qpart * cs.y + qv * cs.x);
  float kr = (lane < 32) ? (kv * cs.x - kpart * cs.y) : (kpart * cs.y + kv * cs.x);
  float kss = wred(kr * kr);
  float kn = kr * rsqrtf(kss * (1.0f / HDIM) + 1e-5f) * kn_w[lane];
  float vss = wred(vv * vv);
  float vn = vv * rsqrtf(vss * (1.0f / HDIM) + 1e-5f) * vn_w[lane];
  size_t dst = ((size_t)(b * NHD + h) * SEQT + t) * HDIM + lane;
  qh[dst] = qr;
  kh[dst] = kn;
  vh[dst] = vn;
  float knss = wred(kn * kn);
  float vnss = wred(vn * vn);
  float qkdot = wred(qr * kn);
  if (lane == 0) {
    size_t sdst = (size_t)(b * NHD + h) * SEQT + t;
    qkd[sdst] = qkdot;
    kvq[sdst] = knss * vnss;
  }
  if (lane < 4) {
    int col = h * 4 + lane;
    float pa = a_pre[(size_t)(b * SEQT + t) * 32 + col] + ab[col];
    float al = 1.0f / (1.0f + expf(-pa));
    al = fminf(fmaxf(al, 1e-4f), 0.9995f);
    float pm = m_pre[(size_t)(b * SEQT + t) * 32 + col] + mb[col];
    float mx = pm;
    mx = fmaxf(mx, __shfl_xor(mx, 1, 64));
    mx = fmaxf(mx, __shfl_xor(mx, 2, 64));
    float e = expf(pm - mx);
    float sum = e;
    sum += __shfl_xor(sum, 1, 64);
    sum += __shfl_xor(sum, 2, 64);
    size_t adst = ((size_t)(b * NHD + h) * KTSN + lane) * SEQT + t;
    av[adst] = al;
    mv[adst] = e / sum;
  }
}

// ---------------- K3c: cross-step scalars ----------------
__global__ __launch_bounds__(256) void k_cross(
    const float* __restrict__ qh, const float* __restrict__ kh, const float* __restrict__ vh,
    float* __restrict__ kkx, float* __restrict__ vvx, float* __restrict__ qxx) {
  int wid = blockIdx.x * 4 + (threadIdx.x >> 6);  // one wave per (bh, t); 16384 waves
  int lane = threadIdx.x & 63;
  int bh = wid >> 10;
  int t = wid & 1023;
  size_t sidx = (size_t)bh * SEQT + t;
  if (t == 0) {
    if (lane == 0) { kkx[sidx] = 0.f; vvx[sidx] = 0.f; qxx[sidx] = 0.f; }
    return;
  }
  size_t base = (size_t)bh * SEQT * HDIM;
  float kc = kh[base + (size_t)t * HDIM + lane];
  float kp = kh[base + (size_t)(t - 1) * HDIM + lane];
  float vc = vh[base + (size_t)t * HDIM + lane];
  float vpv = vh[base + (size_t)(t - 1) * HDIM + lane];
  float qc = qh[base + (size_t)t * HDIM + lane];
  float s1 = wred(kc * kp);
  float s2 = wred(vc * vpv);
  float s3 = wred(qc * kp);
  if (lane == 0) { kkx[sidx] = s1; vvx[sidx] = s2; qxx[sidx] = s3; }
}

// ---------------- K4: scan, 2-STEP ROUNDS x TWO PHASE-SHIFTED CELLS per block ----------------
// Block owns cells A,B = kt {2p, 2p+1} of one (b,h): k/q/v/mask/qk/kv/cross
// stages SHARED; only alpha/mix per-cell. Per round: waitA -> computeA ->
// incA -> waitB -> computeB -> incB. The wait for each cell's counter sits
// ~600 instr after everyone's increment (hidden by the other cell's work),
// so the ~870cyc sync latency overlaps compute instead of serializing
// (r14's fusion failure mode avoided). r19-proven 2-step algebra per cell.
#define G16P(X) \
  X(0, 0) X(1, 1) X(2, 2) X(3, 3) X(4, 0) X(5, 1) X(6, 2) X(7, 3) \
  X(8, 0) X(9, 1) X(10, 2) X(11, 3) X(12, 0) X(13, 1) X(14, 2) X(15, 3)

#define DECLH(g, a) float hA##g = 0.f, hB##g = 0.f;
#define HUP0A(g, a) hA##g = fmaf(hA##g, ag0, rlane(kqj0, (g)) * vm0);
#define HUP1A(g, a) hA##g = fmaf(hA##g, ag1, rlane(kqj1, (g)) * vm1);
#define HUP0B(g, a) hB##g = fmaf(hB##g, ag0, rlane(kqj0, (g)) * vm0);
#define HUP1B(g, a) hB##g = fmaf(hB##g, ag1, rlane(kqj1, (g)) * vm1);
#define MV4A(g, a)                                  \
  {                                                 \
    float k2_ = rlane(kqj2, (g));                   \
    float q2_ = rlane(kqj2, 16 + (g));              \
    float k3_ = rlane(kqj3, (g));                   \
    float q3_ = rlane(kqj3, 16 + (g));              \
    zk2##a = fmaf(k2_, hA##g, zk2##a);              \
    zk3##a = fmaf(k3_, hA##g, zk3##a);              \
    pv2##a = fmaf(q2_, hA##g, pv2##a);              \
    pv3##a = fmaf(q3_, hA##g, pv3##a);              \
  }
#define MV4B(g, a)                                  \
  {                                                 \
    float k2_ = rlane(kqj2, (g));                   \
    float q2_ = rlane(kqj2, 16 + (g));              \
    float k3_ = rlane(kqj3, (g));                   \
    float q3_ = rlane(kqj3, 16 + (g));              \
    zk2##a = fmaf(k2_, hB##g, zk2##a);              \
    zk3##a = fmaf(k3_, hB##g, zk3##a);              \
    pv2##a = fmaf(q2_, hB##g, pv2##a);              \
    pv3##a = fmaf(q3_, hB##g, pv3##a);              \
  }

__global__ __launch_bounds__(256, 1) void k_scan(
    const float* __restrict__ qh, const float* __restrict__ kh, const float* __restrict__ vh,
    const float* __restrict__ av, const float* __restrict__ mv, const int* __restrict__ mask,
    const float* __restrict__ qkd, const float* __restrict__ kvq,
    const float* __restrict__ kkx, const float* __restrict__ vvx, const float* __restrict__ qxx,
    float* __restrict__ y0p, float* __restrict__ y1p, float* __restrict__ y2p,
    float* __restrict__ y3p) {
  int bhp = blockIdx.x;  // bh*2 + pair
  int bh = bhp >> 1;
  int pair = bhp & 1;    // cells A,B = kt 2*pair, 2*pair+1
  int b = bh >> 3;
  int h = bh & 7;
  int tid = threadIdx.x;
  int w = tid >> 6;     // wave id: owns d in [16w,16w+16) of both cells
  int lane = tid & 63;  // = e
  int dbase = w * 16;

  const float* kp = kh + (size_t)bh * SEQT * HDIM;
  const float* qp = qh + (size_t)bh * SEQT * HDIM;
  const float* vp = vh + (size_t)bh * SEQT * HDIM;
  const float* apA = av + (size_t)(bh * 4 + 2 * pair + 0) * SEQT;
  const float* apB = av + (size_t)(bh * 4 + 2 * pair + 1) * SEQT;
  const float* mpA = mv + (size_t)(bh * 4 + 2 * pair + 0) * SEQT;
  const float* mpB = mv + (size_t)(bh * 4 + 2 * pair + 1) * SEQT;
  const float* qkp = qkd + (size_t)bh * SEQT;
  const float* kvp = kvq + (size_t)bh * SEQT;
  const float* kkp = kkx + (size_t)bh * SEQT;
  const float* vvp = vvx + (size_t)bh * SEQT;
  const float* qxp = qxx + (size_t)bh * SEQT;
  const int* mk = mask + (size_t)b * SEQT;
  float* yselA = (pair == 0) ? y0p : y2p;
  float* yselB = (pair == 0) ? y1p : y3p;
  float* ypoA = yselA + (size_t)(b * SEQT) * HIDN + h * HDIM + lane;
  float* ypoB = yselB + (size_t)(b * SEQT) * HIDN + h * HDIM + lane;

  __shared__ __align__(16) float2 ZA[2][4];         // [P][w] = {Z0, Z1}
  __shared__ __align__(16) float2 ZB[2][4];
  __shared__ __align__(16) float PbA[2][2][4][64];  // [P][which][w][e]
  __shared__ __align__(16) float PbB[2][2][4][64];
  __shared__ int cntA, cntB;

  G16P(DECLH)  // hA0..hA15, hB0..hB15
  float gprevA = 1.0f, usqA = 0.0f;
  float gprevB = 1.0f, usqB = 0.0f;

  // lanes 0-15: k-slice; 16-31: q-slice; 32-63 duplicate.
  int off = lane & 15;
  const float* kqbase = ((lane >> 4) & 1) ? qp : kp;
  int kqidx = dbase + off;

  // shared stages j0..j5 = steps s..s+5 (round r: s = 2r)
  float kqj0 = kqbase[kqidx];
  float kqj1 = kqbase[(size_t)1 * HDIM + kqidx];
  float kqj2 = kqbase[(size_t)2 * HDIM + kqidx];
  float kqj3 = kqbase[(size_t)3 * HDIM + kqidx];
  float kqj4 = kqbase[(size_t)4 * HDIM + kqidx];
  float kqj5 = kqbase[(size_t)5 * HDIM + kqidx];
  float vj0 = vp[lane], vj1 = vp[HDIM + lane], vj2 = vp[2 * HDIM + lane];
  float vj3 = vp[3 * HDIM + lane], vj4 = vp[4 * HDIM + lane], vj5 = vp[5 * HDIM + lane];
  float m0 = (float)mk[0], m1 = (float)mk[1], m2 = (float)mk[2];
  float m3 = (float)mk[3], m4 = (float)mk[4], m5 = (float)mk[5];
  float qk0 = qkp[0], qk1 = qkp[1], qk2 = qkp[2], qk3 = qkp[3], qk4 = qkp[4], qk5 = qkp[5];
  float kv0 = kvp[0], kv1 = kvp[1], kv2 = kvp[2], kv3 = kvp[3], kv4 = kvp[4], kv5 = kvp[5];
  float kko0 = kkp[1], kko1 = kkp[3], kko2 = kkp[5];
  float vvo0 = vvp[1], vvo1 = vvp[3], vvo2 = vvp[5];
  float qxo0 = qxp[1], qxo1 = qxp[3], qxo2 = qxp[5];
  // per-cell stages
  float aA0 = apA[0], aA1 = apA[1], aA2 = apA[2], aA3 = apA[3], aA4 = apA[4], aA5 = apA[5];
  float aB0 = apB[0], aB1 = apB[1], aB2 = apB[2], aB3 = apB[3], aB4 = apB[4], aB5 = apB[5];
  float mxA0 = mpA[0], mxA1 = mpA[1], mxA2 = mpA[2], mxA3 = mpA[3], mxA4 = mpA[4], mxA5 = mpA[5];
  float mxB0 = mpB[0], mxB1 = mpB[1], mxB2 = mpB[2], mxB3 = mpB[3], mxB4 = mpB[4], mxB5 = mpB[5];

  if (tid == 0) { cntA = 0; cntB = 0; }
  if (lane == 0) { ZA[0][w] = make_float2(0.f, 0.f); ZB[0][w] = make_float2(0.f, 0.f); }
  PbA[0][0][w][lane] = 0.f; PbA[0][1][w][lane] = 0.f;
  PbB[0][0][w][lane] = 0.f; PbB[0][1][w][lane] = 0.f;
  __syncthreads();

  for (int s = 0; s < SEQT; s += 2) {
    int r = s >> 1;
    int P = r & 1;
    int t6 = s + 6, t7 = s + 7;
    if (t6 > SEQT - 1) t6 = SEQT - 1;
    if (t7 > SEQT - 1) t7 = SEQT - 1;
    // shared prefetch
    float kqN6 = kqbase[(size_t)t6 * HDIM + kqidx];
    float kqN7 = kqbase[(size_t)t7 * HDIM + kqidx];
    float vN6 = vp[(size_t)t6 * HDIM + lane];
    float vN7 = vp[(size_t)t7 * HDIM + lane];
    float mN6 = (float)mk[t6], mN7 = (float)mk[t7];
    float qkN6 = qkp[t6], qkN7 = qkp[t7];
    float kvN6 = kvp[t6], kvN7 = kvp[t7];
    float kkN = kkp[t7], vvN = vvp[t7], qxN = qxp[t7];
    float aAN6 = apA[t6], aAN7 = apA[t7], aBN6 = apB[t6], aBN7 = apB[t7];
    float mxAN6 = mpA[t6], mxAN7 = mpA[t7], mxBN6 = mpB[t6], mxBN7 = mpB[t7];

    float vm0 = m0 * vj0;  // shared by both cells
    float vm1 = m1 * vj1;

    // ================= cell A phase =================
    {
      int target = 4 * r;
      while (*(volatile int*)&cntA < target) {
      }
    }
    asm volatile("" ::: "memory");
    {
      float2 zb0 = ZA[P][0], zb1 = ZA[P][1], zb2 = ZA[P][2], zb3 = ZA[P][3];
      float zs = (zb0.x + zb1.x) + (zb2.x + zb3.x);
      float w1 = (zb0.y + zb1.y) + (zb2.y + zb3.y);

      float ag0 = aA0 * gprevA;
      G16P(HUP0A)
      float usq0 = fmaf(ag0 * ag0, usqA, fmaf(2.0f * ag0 * m0, zs, (m0 * m0) * kv0));
      usq0 = fmaxf(usq0, 0.0f);
      float g0 = fminf(16.0f * rsqrtf(usq0), 1.0f);

      float z1 = fmaf(ag0, w1, (m0 * kko0) * vvo0);
      float ag1 = aA1 * g0;
      G16P(HUP1A)
      float usq1 = fmaf(ag1 * ag1, usq0, fmaf(2.0f * ag1 * m1, z1, (m1 * m1) * kv1));
      usq1 = fmaxf(usq1, 0.0f);
      float g1 = fminf(16.0f * rsqrtf(usq1), 1.0f);

      float zk20 = 0.f, zk21 = 0.f, zk22 = 0.f, zk23 = 0.f;
      float zk30 = 0.f, zk31 = 0.f, zk32 = 0.f, zk33 = 0.f;
      float pv20 = 0.f, pv21 = 0.f, pv22 = 0.f, pv23 = 0.f;
      float pv30 = 0.f, pv31 = 0.f, pv32 = 0.f, pv33 = 0.f;
      G16P(MV4A)
      float Z0n = wsum64_fast(((zk20 + zk21) + (zk22 + zk23)) * vj2);
      float Z1n = wsum64_fast(((zk30 + zk31) + (zk32 + zk33)) * vj3);
      float P0n = (pv20 + pv21) + (pv22 + pv23);
      float P1n = (pv30 + pv31) + (pv32 + pv33);

      if (w == 0) {
        float pe = (PbA[P][0][0][lane] + PbA[P][0][1][lane]) +
                   (PbA[P][0][2][lane] + PbA[P][0][3][lane]);
        ypoA[(size_t)s * HIDN] = (g0 * mxA0) * fmaf(ag0, pe, (m0 * qk0) * vj0);
      } else if (w == 1) {
        float pe = (PbA[P][1][0][lane] + PbA[P][1][1][lane]) +
                   (PbA[P][1][2][lane] + PbA[P][1][3][lane]);
        float p1 = fmaf(ag0, pe, (m0 * qxo0) * vj0);
        ypoA[(size_t)(s + 1) * HIDN] = (g1 * mxA1) * fmaf(ag1, p1, (m1 * qk1) * vj1);
      }

      if (lane == 0) ZA[P ^ 1][w] = make_float2(Z0n, Z1n);
      PbA[P ^ 1][0][w][lane] = P0n;
      PbA[P ^ 1][1][w][lane] = P1n;
      asm volatile("s_waitcnt lgkmcnt(0)" ::: "memory");
      if (lane == 0) atomicAdd(&cntA, 1);
      gprevA = g1;
      usqA = usq1;
    }

    // ================= cell B phase =================
    {
      int target = 4 * r;
      while (*(volatile int*)&cntB < target) {
      }
    }
    asm volatile("" ::: "memory");
    {
      float2 zb0 = ZB[P][0], zb1 = ZB[P][1], zb2 = ZB[P][2], zb3 = ZB[P][3];
      float zs = (zb0.x + zb1.x) + (zb2.x + zb3.x);
      float w1 = (zb0.y + zb1.y) + (zb2.y + zb3.y);

      float ag0 = aB0 * gprevB;
      G16P(HUP0B)
      float usq0 = fmaf(ag0 * ag0, usqB, fmaf(2.0f * ag0 * m0, zs, (m0 * m0) * kv0));
      usq0 = fmaxf(usq0, 0.0f);
      float g0 = fminf(16.0f * rsqrtf(usq0), 1.0f);

      float z1 = fmaf(ag0, w1, (m0 * kko0) * vvo0);
      float ag1 = aB1 * g0;
      G16P(HUP1B)
      float usq1 = fmaf(ag1 * ag1, usq0, fmaf(2.0f * ag1 * m1, z1, (m1 * m1) * kv1));
      usq1 = fmaxf(usq1, 0.0f);
      float g1 = fminf(16.0f * rsqrtf(usq1), 1.0f);

      float zk20 = 0.f, zk21 = 0.f, zk22 = 0.f, zk23 = 0.f;
      float zk30 = 0.f, zk31 = 0.f, zk32 = 0.f, zk33 = 0.f;
      float pv20 = 0.f, pv21 = 0.f, pv22 = 0.f, pv23 = 0.f;
      float pv30 = 0.f, pv31 = 0.f, pv32 = 0.f, pv33 = 0.f;
      G16P(MV4B)
      float Z0n = wsum64_fast(((zk20 + zk21) + (zk22 + zk23)) * vj2);
      float Z1n = wsum64_fast(((zk30 + zk31) + (zk32 + zk33)) * vj3);
      float P0n = (pv20 + pv21) + (pv22 + pv23);
      float P1n = (pv30 + pv31) + (pv32 + pv33);

      if (w == 2) {
        float pe = (PbB[P][0][0][lane] + PbB[P][0][1][lane]) +
                   (PbB[P][0][2][lane] + PbB[P][0][3][lane]);
        ypoB[(size_t)s * HIDN] = (g0 * mxB0) * fmaf(ag0, pe, (m0 * qk0) * vj0);
      } else if (w == 3) {
        float pe = (PbB[P][1][0][lane] + PbB[P][1][1][lane]) +
                   (PbB[P][1][2][lane] + PbB[P][1][3][lane]);
        float p1 = fmaf(ag0, pe, (m0 * qxo0) * vj0);
        ypoB[(size_t)(s + 1) * HIDN] = (g1 * mxB1) * fmaf(ag1, p1, (m1 * qk1) * vj1);
      }

      if (lane == 0) ZB[P ^ 1][w] = make_float2(Z0n, Z1n);
      PbB[P ^ 1][0][w][lane] = P0n;
      PbB[P ^ 1][1][w][lane] = P1n;
      asm volatile("s_waitcnt lgkmcnt(0)" ::: "memory");
      if (lane == 0) atomicAdd(&cntB, 1);
      gprevB = g1;
      usqB = usq1;
    }

    // rotate shared + per-cell stages
    kqj0 = kqj2; kqj1 = kqj3; kqj2 = kqj4; kqj3 = kqj5; kqj4 = kqN6; kqj5 = kqN7;
    vj0 = vj2; vj1 = vj3; vj2 = vj4; vj3 = vj5; vj4 = vN6; vj5 = vN7;
    m0 = m2; m1 = m3; m2 = m4; m3 = m5; m4 = mN6; m5 = mN7;
    qk0 = qk2; qk1 = qk3; qk2 = qk4; qk3 = qk5; qk4 = qkN6; qk5 = qkN7;
    kv0 = kv2; kv1 = kv3; kv2 = kv4; kv3 = kv5; kv4 = kvN6; kv5 = kvN7;
    kko0 = kko1; kko1 = kko2; kko2 = kkN;
    vvo0 = vvo1; vvo1 = vvo2; vvo2 = vvN;
    qxo0 = qxo1; qxo1 = qxo2; qxo2 = qxN;
    aA0 = aA2; aA1 = aA3; aA2 = aA4; aA3 = aA5; aA4 = aAN6; aA5 = aAN7;
    aB0 = aB2; aB1 = aB3; aB2 = aB4; aB3 = aB5; aB4 = aBN6; aB5 = aBN7;
    mxA0 = mxA2; mxA1 = mxA3; mxA2 = mxA4; mxA3 = mxA5; mxA4 = mxAN6; mxA5 = mxAN7;
    mxB0 = mxB2; mxB1 = mxB3; mxB2 = mxB4; mxB3 = mxB5; mxB4 = mxBN6; mxB5 = mxBN7;
  }
}

// ---------------- K5: r = x + (sum_kt y) @ oW^T + ob ----------------
__global__ __launch_bounds__(256) void k_gemm_out(
    const float* __restrict__ y0, const float* __restrict__ y1,
    const float* __restrict__ y2, const float* __restrict__ y3,
    const float* __restrict__ oW, const float* __restrict__ ob,
    const float* __restrict__ x, float* __restrict__ r) {
  __shared__ __align__(16) float As[32][68];
  __shared__ __align__(16) float Bs[32][68];
  int tid = threadIdx.x;
  int m0 = blockIdx.x * 64, n0 = blockIdx.y * 64;
  int tm = tid >> 4, tn = tid & 15;
  float acc[4][4] = {};
  int rr = tid >> 2, cc = (tid & 3) * 8;
  for (int k0 = 0; k0 < HIDN; k0 += 32) {
    size_t aoff = (size_t)(m0 + rr) * HIDN + k0 + cc;
#pragma unroll
    for (int half = 0; half < 2; ++half) {
      size_t sh = aoff + half * 4;
      float4 p0 = *(const float4*)(y0 + sh);
      float4 p1 = *(const float4*)(y1 + sh);
      float4 p2 = *(const float4*)(y2 + sh);
      float4 p3 = *(const float4*)(y3 + sh);
      int cbase = cc + half * 4;
      As[cbase + 0][rr] = p0.x + p1.x + p2.x + p3.x;
      As[cbase + 1][rr] = p0.y + p1.y + p2.y + p3.y;
      As[cbase + 2][rr] = p0.z + p1.z + p2.z + p3.z;
      As[cbase + 3][rr] = p0.w + p1.w + p2.w + p3.w;
    }
    const float* s1 = oW + (size_t)(n0 + rr) * HIDN + k0 + cc;
    float4 b0 = *(const float4*)s1;
    float4 b1 = *(const float4*)(s1 + 4);
    Bs[cc + 0][rr] = b0.x; Bs[cc + 1][rr] = b0.y; Bs[cc + 2][rr] = b0.z; Bs[cc + 3][rr] = b0.w;
    Bs[cc + 4][rr] = b1.x; Bs[cc + 5][rr] = b1.y; Bs[cc + 6][rr] = b1.z; Bs[cc + 7][rr] = b1.w;
    __syncthreads();
#pragma unroll
    for (int kk = 0; kk < 32; ++kk) {
      float4 a4 = *(const float4*)&As[kk][tm * 4];
      float4 b4 = *(const float4*)&Bs[kk][tn * 4];
      float aa[4] = {a4.x, a4.y, a4.z, a4.w};
      float bb[4] = {b4.x, b4.y, b4.z, b4.w};
#pragma unroll
      for (int i = 0; i < 4; ++i)
#pragma unroll
        for (int j = 0; j < 4; ++j) acc[i][j] += aa[i] * bb[j];
    }
    __syncthreads();
  }
#pragma unroll
  for (int i = 0; i < 4; ++i) {
    int mr = m0 + tm * 4 + i;
#pragma unroll
    for (int j = 0; j < 4; ++j) {
      int nc = n0 + tn * 4 + j;
      r[(size_t)mr * HIDN + nc] = x[(size_t)mr * HIDN + nc] + acc[i][j] + ob[nc];
    }
  }
}

// ---------------- K6: LayerNorm -> out ----------------
__global__ __launch_bounds__(256) void k_layernorm(
    const float* __restrict__ r, const float* __restrict__ w, const float* __restrict__ bb,
    float* __restrict__ out) {
  int m = blockIdx.x;
  int tid = threadIdx.x;
  const float* row = r + (size_t)m * HIDN;
  float2 v = *(const float2*)(row + tid * 2);
  float s = wred(v.x + v.y);
  float ss = wred(v.x * v.x + v.y * v.y);
  __shared__ float r1[4], r2[4];
  int lane = tid & 63, wv = tid >> 6;
  if (lane == 0) {
    r1[wv] = s;
    r2[wv] = ss;
  }
  __syncthreads();
  float S = r1[0] + r1[1] + r1[2] + r1[3];
  float SS = r2[0] + r2[1] + r2[2] + r2[3];
  float mu = S * (1.0f / HIDN);
  float var = SS * (1.0f / HIDN) - mu * mu;
  float inv = rsqrtf(var + 1e-5f);
  float2 w2 = *(const float2*)(w + tid * 2);
  float2 b2 = *(const float2*)(bb + tid * 2);
  float2 o;
  o.x = (v.x - mu) * inv * w2.x + b2.x;
  o.y = (v.y - mu) * inv * w2.y + b2.y;
  *(float2*)(out + (size_t)m * HIDN + tid * 2) = o;
}

// ---------------- launch ----------------
extern "C" void kernel_launch(void* const* d_in, const int* in_sizes, int n_in,
                              void* d_out, int out_size, void* d_ws, size_t ws_size,
                              hipStream_t stream) {
  const float* x = (const float*)d_in[0];
  const float* in_w = (const float*)d_in[1];
  const float* qW = (const float*)d_in[2];
  const float* kW = (const float*)d_in[3];
  const float* vW = (const float*)d_in[4];
  const float* aW = (const float*)d_in[5];
  const float* ab = (const float*)d_in[6];
  const float* mW = (const float*)d_in[7];
  const float* mb = (const float*)d_in[8];
  const float* oW = (const float*)d_in[9];
  const float* ob = (const float*)d_in[10];
  const float* kn_w = (const float*)d_in[11];
  const float* vn_w = (const float*)d_in[12];
  const float* ln_w = (const float*)d_in[13];
  const float* ln_b = (const float*)d_in[14];
  const int* mask = (const int*)d_in[15];

  float* ws = (float*)d_ws;
  float* xn = ws + 0;
  float* qb = ws + 1048576;
  float* kb = ws + 2097152;
  float* vb = ws + 3145728;
  float* apre = ws + 4194304;
  float* mpre = ws + 4259840;
  float2* tab = (float2*)(ws + 4325376);
  float* qh = ws + 4390912;
  float* kh = ws + 5439488;
  float* vh = ws + 6488064;
  float* avv = ws + 7536640;
  float* mvv = ws + 7602176;
  float* y3 = ws + 7667712;
  float* y0 = qb;
  float* y1 = kb;
  float* y2 = vb;
  float* rr = xn;
  float* qkd = ws + 0;
  float* kvq = ws + 16384;
  float* kkx = ws + 32768;
  float* vvx = ws + 49152;
  float* qxx = ws + 65536;

  k_rope_table<<<128, 256, 0, stream>>>(tab);
  k_rmsnorm_in<<<NTOK, 256, 0, stream>>>(x, in_w, xn);
  dim3 gBig(32, 8);
  k_gemm_qkv<<<gBig, 256, 0, stream>>>(xn, qW, kW, vW, qb, kb, vb);
  k_gemm_am<<<32, 256, 0, stream>>>(xn, aW, mW, apre, mpre);
  k_postproc<<<4096, 256, 0, stream>>>(qb, kb, vb, apre, mpre, ab, mb, kn_w, vn_w, tab,
                                       qh, kh, vh, avv, mvv, qkd, kvq);
  k_cross<<<4096, 256, 0, stream>>>(qh, kh, vh, kkx, vvx, qxx);
  k_scan<<<32, 256, 0, stream>>>(qh, kh, vh, avv, mvv, mask, qkd, kvq, kkx, vvx, qxx,
                                 y0, y1, y2, y3);
  k_gemm_out<<<gBig, 256, 0, stream>>>(y0, y1, y2, y3, oW, ob, x, rr);
  k_layernorm<<<NTOK, 256, 0, stream>>>(rr, ln_w, ln_b, (float*)d_out);
  (void)in_sizes; (void)n_in; (void)out_size; (void)ws_size;
}

// Round 22
// 701.700 us; speedup vs baseline: 1.9698x; 1.9698x over previous
//
#include <hip/hip_runtime.h>
#include <math.h>

#define SEQT 1024
#define NTOK 2048
#define HIDN 512
#define NHD 8
#define HDIM 64
#define KTSN 4

__device__ __forceinline__ float wred(float v) {
#pragma unroll
  for (int off = 32; off; off >>= 1) v += __shfl_xor(v, off, 64);
  return v;
}

// rotation-allreduce within rows of 16 via DPP (VALU-speed)
template <int CTRL>
__device__ __forceinline__ float rra(float v) {
  return v + __int_as_float(__builtin_amdgcn_update_dpp(
                 0, __float_as_int(v), CTRL, 0xf, 0xf, true));
}
__device__ __forceinline__ float rlane(float v, int l) {
  return __int_as_float(__builtin_amdgcn_readlane(__float_as_int(v), l));
}
// full-wave sum: 4 DPP row_rors (row sums) + 4 readlanes + adds.
__device__ __forceinline__ float wsum64_fast(float v) {
  v = rra<0x121>(v);  // row_ror:1
  v = rra<0x122>(v);  // row_ror:2
  v = rra<0x124>(v);  // row_ror:4
  v = rra<0x128>(v);  // row_ror:8  -> each lane has its 16-lane row sum
  return (rlane(v, 0) + rlane(v, 16)) + (rlane(v, 32) + rlane(v, 48));
}

// ---------------- K1: input RMSNorm (one block per row) ----------------
__global__ __launch_bounds__(256) void k_rmsnorm_in(
    const float* __restrict__ x, const float* __restrict__ w, float* __restrict__ xn) {
  int m = blockIdx.x;
  int tid = threadIdx.x;
  const float* row = x + (size_t)m * HIDN;
  float2 v = *(const float2*)(row + tid * 2);
  float ss = wred(v.x * v.x + v.y * v.y);
  __shared__ float red[4];
  int lane = tid & 63, wv = tid >> 6;
  if (lane == 0) red[wv] = ss;
  __syncthreads();
  float tot = red[0] + red[1] + red[2] + red[3];
  float inv = rsqrtf(tot * (1.0f / HIDN) + 1e-5f);
  float2 wv2 = *(const float2*)(w + tid * 2);
  float2 o;
  o.x = v.x * inv * wv2.x;
  o.y = v.y * inv * wv2.y;
  *(float2*)(xn + (size_t)m * HIDN + tid * 2) = o;
}

// ---------------- K2a: fused QKV GEMM ----------------
__global__ __launch_bounds__(256) void k_gemm_qkv(
    const float* __restrict__ A, const float* __restrict__ Bq,
    const float* __restrict__ Bk, const float* __restrict__ Bv,
    float* __restrict__ Cq, float* __restrict__ Ck, float* __restrict__ Cv) {
  __shared__ __align__(16) float As[32][68];
  __shared__ __align__(16) float Bs0[32][68];
  __shared__ __align__(16) float Bs1[32][68];
  __shared__ __align__(16) float Bs2[32][68];
  int tid = threadIdx.x;
  int m0 = blockIdx.x * 64, n0 = blockIdx.y * 64;
  int tm = tid >> 4, tn = tid & 15;
  float aq[4][4] = {}, ak[4][4] = {}, av4[4][4] = {};
  int rr = tid >> 2, cc = (tid & 3) * 8;
  for (int k0 = 0; k0 < HIDN; k0 += 32) {
    const float* s0 = A + (size_t)(m0 + rr) * HIDN + k0 + cc;
    float4 a0 = *(const float4*)s0;
    float4 a1 = *(const float4*)(s0 + 4);
    As[cc + 0][rr] = a0.x; As[cc + 1][rr] = a0.y; As[cc + 2][rr] = a0.z; As[cc + 3][rr] = a0.w;
    As[cc + 4][rr] = a1.x; As[cc + 5][rr] = a1.y; As[cc + 6][rr] = a1.z; As[cc + 7][rr] = a1.w;
    size_t boff = (size_t)(n0 + rr) * HIDN + k0 + cc;
    float4 b0 = *(const float4*)(Bq + boff);
    float4 b1 = *(const float4*)(Bq + boff + 4);
    Bs0[cc + 0][rr] = b0.x; Bs0[cc + 1][rr] = b0.y; Bs0[cc + 2][rr] = b0.z; Bs0[cc + 3][rr] = b0.w;
    Bs0[cc + 4][rr] = b1.x; Bs0[cc + 5][rr] = b1.y; Bs0[cc + 6][rr] = b1.z; Bs0[cc + 7][rr] = b1.w;
    b0 = *(const float4*)(Bk + boff);
    b1 = *(const float4*)(Bk + boff + 4);
    Bs1[cc + 0][rr] = b0.x; Bs1[cc + 1][rr] = b0.y; Bs1[cc + 2][rr] = b0.z; Bs1[cc + 3][rr] = b0.w;
    Bs1[cc + 4][rr] = b1.x; Bs1[cc + 5][rr] = b1.y; Bs1[cc + 6][rr] = b1.z; Bs1[cc + 7][rr] = b1.w;
    b0 = *(const float4*)(Bv + boff);
    b1 = *(const float4*)(Bv + boff + 4);
    Bs2[cc + 0][rr] = b0.x; Bs2[cc + 1][rr] = b0.y; Bs2[cc + 2][rr] = b0.z; Bs2[cc + 3][rr] = b0.w;
    Bs2[cc + 4][rr] = b1.x; Bs2[cc + 5][rr] = b1.y; Bs2[cc + 6][rr] = b1.z; Bs2[cc + 7][rr] = b1.w;
    __syncthreads();
#pragma unroll
    for (int kk = 0; kk < 32; ++kk) {
      float4 a4 = *(const float4*)&As[kk][tm * 4];
      float4 q4 = *(const float4*)&Bs0[kk][tn * 4];
      float4 k4 = *(const float4*)&Bs1[kk][tn * 4];
      float4 v4 = *(const float4*)&Bs2[kk][tn * 4];
      float aa[4] = {a4.x, a4.y, a4.z, a4.w};
      float qq[4] = {q4.x, q4.y, q4.z, q4.w};
      float kk_[4] = {k4.x, k4.y, k4.z, k4.w};
      float vv[4] = {v4.x, v4.y, v4.z, v4.w};
#pragma unroll
      for (int i = 0; i < 4; ++i)
#pragma unroll
        for (int j = 0; j < 4; ++j) {
          aq[i][j] = fmaf(aa[i], qq[j], aq[i][j]);
          ak[i][j] = fmaf(aa[i], kk_[j], ak[i][j]);
          av4[i][j] = fmaf(aa[i], vv[j], av4[i][j]);
        }
    }
    __syncthreads();
  }
#pragma unroll
  for (int i = 0; i < 4; ++i) {
    size_t mr = (size_t)(m0 + tm * 4 + i) * HIDN;
#pragma unroll
    for (int j = 0; j < 4; ++j) {
      int nc = n0 + tn * 4 + j;
      Cq[mr + nc] = aq[i][j];
      Ck[mr + nc] = ak[i][j];
      Cv[mr + nc] = av4[i][j];
    }
  }
}

// ---------------- K2b: fused alpha/mix GEMM ----------------
__global__ __launch_bounds__(256) void k_gemm_am(
    const float* __restrict__ A, const float* __restrict__ Ba,
    const float* __restrict__ Bm, float* __restrict__ Ca, float* __restrict__ Cm) {
  __shared__ __align__(16) float As[32][68];
  __shared__ __align__(16) float Bs[32][68];
  int tid = threadIdx.x;
  int m0 = blockIdx.x * 64;
  int tm = tid >> 4, tn = tid & 15;
  float acc[4][4] = {};
  int rr = tid >> 2, cc = (tid & 3) * 8;
  for (int k0 = 0; k0 < HIDN; k0 += 32) {
    const float* s0 = A + (size_t)(m0 + rr) * HIDN + k0 + cc;
    float4 a0 = *(const float4*)s0;
    float4 a1 = *(const float4*)(s0 + 4);
    As[cc + 0][rr] = a0.x; As[cc + 1][rr] = a0.y; As[cc + 2][rr] = a0.z; As[cc + 3][rr] = a0.w;
    As[cc + 4][rr] = a1.x; As[cc + 5][rr] = a1.y; As[cc + 6][rr] = a1.z; As[cc + 7][rr] = a1.w;
    const float* s1 = ((rr < 32) ? (Ba + (size_t)rr * HIDN) : (Bm + (size_t)(rr - 32) * HIDN)) + k0 + cc;
    float4 b0 = *(const float4*)s1;
    float4 b1 = *(const float4*)(s1 + 4);
    Bs[cc + 0][rr] = b0.x; Bs[cc + 1][rr] = b0.y; Bs[cc + 2][rr] = b0.z; Bs[cc + 3][rr] = b0.w;
    Bs[cc + 4][rr] = b1.x; Bs[cc + 5][rr] = b1.y; Bs[cc + 6][rr] = b1.z; Bs[cc + 7][rr] = b1.w;
    __syncthreads();
#pragma unroll
    for (int kk = 0; kk < 32; ++kk) {
      float4 a4 = *(const float4*)&As[kk][tm * 4];
      float4 b4 = *(const float4*)&Bs[kk][tn * 4];
      float aa[4] = {a4.x, a4.y, a4.z, a4.w};
      float bb[4] = {b4.x, b4.y, b4.z, b4.w};
#pragma unroll
      for (int i = 0; i < 4; ++i)
#pragma unroll
        for (int j = 0; j < 4; ++j) acc[i][j] = fmaf(aa[i], bb[j], acc[i][j]);
    }
    __syncthreads();
  }
#pragma unroll
  for (int i = 0; i < 4; ++i) {
    int mr = m0 + tm * 4 + i;
#pragma unroll
    for (int j = 0; j < 4; ++j) {
      int nc = tn * 4 + j;
      if (nc < 32)
        Ca[(size_t)mr * 32 + nc] = acc[i][j];
      else
        Cm[(size_t)mr * 32 + nc - 32] = acc[i][j];
    }
  }
}

// ---------------- K3a: rope cos/sin table [t][j] ----------------
__global__ __launch_bounds__(256) void k_rope_table(float2* __restrict__ tab) {
  int idx = blockIdx.x * 256 + threadIdx.x;  // 1024*32
  int t = idx >> 5, j = idx & 31;
  float invf = (float)exp2(-(double)j * (13.287712379549449 / 32.0));  // 10000^(-j/32)
  float ang = (float)t * invf;                                         // fp32, matches ref
  double s, c;
  sincos((double)ang, &s, &c);
  tab[idx] = make_float2((float)c, (float)s);
}

// ---------------- K3b: rope(q,k), rmsnorm(k,v), alpha, mix; transpose; qkd/kvq scalars ----------------
__global__ __launch_bounds__(256) void k_postproc(
    const float* __restrict__ q_in, const float* __restrict__ k_in, const float* __restrict__ v_in,
    const float* __restrict__ a_pre, const float* __restrict__ m_pre,
    const float* __restrict__ ab, const float* __restrict__ mb,
    const float* __restrict__ kn_w, const float* __restrict__ vn_w,
    const float2* __restrict__ tab,
    float* __restrict__ qh, float* __restrict__ kh, float* __restrict__ vh,
    float* __restrict__ av, float* __restrict__ mv,
    float* __restrict__ qkd, float* __restrict__ kvq) {
  int wid = blockIdx.x * 4 + (threadIdx.x >> 6);  // one wave per (b,t,h)
  int lane = threadIdx.x & 63;
  int b = wid >> 13;
  int rem = wid & 8191;
  int t = rem >> 3;
  int h = rem & 7;
  size_t src = (size_t)(b * SEQT + t) * HIDN + h * HDIM + lane;
  float qv = q_in[src], kv = k_in[src], vv = v_in[src];
  float2 cs = tab[t * 32 + (lane & 31)];
  float qpart = __shfl_xor(qv, 32, 64);
  float kpart = __shfl_xor(kv, 32, 64);
  float qr = (lane < 32) ? (qv * cs.x - qpart * cs.y) : (qpart * cs.y + qv * cs.x);
  float kr = (lane < 32) ? (kv * cs.x - kpart * cs.y) : (kpart * cs.y + kv * cs.x);
  float kss = wred(kr * kr);
  float kn = kr * rsqrtf(kss * (1.0f / HDIM) + 1e-5f) * kn_w[lane];
  float vss = wred(vv * vv);
  float vn = vv * rsqrtf(vss * (1.0f / HDIM) + 1e-5f) * vn_w[lane];
  size_t dst = ((size_t)(b * NHD + h) * SEQT + t) * HDIM + lane;
  qh[dst] = qr;
  kh[dst] = kn;
  vh[dst] = vn;
  float knss = wred(kn * kn);
  float vnss = wred(vn * vn);
  float qkdot = wred(qr * kn);
  if (lane == 0) {
    size_t sdst = (size_t)(b * NHD + h) * SEQT + t;
    qkd[sdst] = qkdot;
    kvq[sdst] = knss * vnss;
  }
  if (lane < 4) {
    int col = h * 4 + lane;
    float pa = a_pre[(size_t)(b * SEQT + t) * 32 + col] + ab[col];
    float al = 1.0f / (1.0f + expf(-pa));
    al = fminf(fmaxf(al, 1e-4f), 0.9995f);
    float pm = m_pre[(size_t)(b * SEQT + t) * 32 + col] + mb[col];
    float mx = pm;
    mx = fmaxf(mx, __shfl_xor(mx, 1, 64));
    mx = fmaxf(mx, __shfl_xor(mx, 2, 64));
    float e = expf(pm - mx);
    float sum = e;
    sum += __shfl_xor(sum, 1, 64);
    sum += __shfl_xor(sum, 2, 64);
    size_t adst = ((size_t)(b * NHD + h) * KTSN + lane) * SEQT + t;
    av[adst] = al;
    mv[adst] = e / sum;
  }
}

// ---------------- K3c: cross-step scalars kk[t]=k_t.k_{t-1}, vv[t]=v_t.v_{t-1}, qx[t]=q_t.k_{t-1} ----------------
__global__ __launch_bounds__(256) void k_cross(
    const float* __restrict__ qh, const float* __restrict__ kh, const float* __restrict__ vh,
    float* __restrict__ kkx, float* __restrict__ vvx, float* __restrict__ qxx) {
  int wid = blockIdx.x * 4 + (threadIdx.x >> 6);  // one wave per (bh, t); 16384 waves
  int lane = threadIdx.x & 63;
  int bh = wid >> 10;
  int t = wid & 1023;
  size_t sidx = (size_t)bh * SEQT + t;
  if (t == 0) {
    if (lane == 0) { kkx[sidx] = 0.f; vvx[sidx] = 0.f; qxx[sidx] = 0.f; }
    return;
  }
  size_t base = (size_t)bh * SEQT * HDIM;
  float kc = kh[base + (size_t)t * HDIM + lane];
  float kp = kh[base + (size_t)(t - 1) * HDIM + lane];
  float vc = vh[base + (size_t)t * HDIM + lane];
  float vpv = vh[base + (size_t)(t - 1) * HDIM + lane];
  float qc = qh[base + (size_t)t * HDIM + lane];
  float s1 = wred(kc * kp);
  float s2 = wred(vc * vpv);
  float s3 = wred(qc * kp);
  if (lane == 0) { kkx[sidx] = s1; vvx[sidx] = s2; qxx[sidx] = s3; }
}

// ---------------- K4: sequential scan, 2-STEP ROUNDS (one exchange per 2 steps) ----------------
// Per round (steps s, s+1), exchange data computed against u_{s-1} at the
// previous round: Z0=(k_s^T u)(.v_s), Z1=(k_{s+1}^T u)(.v_{s+1}),
// P0=q_s^T u, P1=q_{s+1}^T u (partials per wave). Scalar-norm recurrence
// (r16-proven) gives g_s; z_{s+1}/p_{s+1} corrected with precomputed
// cross-scalars kk,vv,qkx. Matvecs for s+2,s+3 run against u_{s+1} and are
// exchanged ONCE. Sync = spin counter (r17-proven == s_barrier cost).
#define G16P(X) \
  X(0, 0) X(1, 1) X(2, 2) X(3, 3) X(4, 0) X(5, 1) X(6, 2) X(7, 3) \
  X(8, 0) X(9, 1) X(10, 2) X(11, 3) X(12, 0) X(13, 1) X(14, 2) X(15, 3)

#define DECLH(g, a) float h##g = 0.f;
#define HUP0(g, a) h##g = fmaf(h##g, ag0, rlane(kqj0, (g)) * vm0);
#define HUP1(g, a) h##g = fmaf(h##g, ag1, rlane(kqj1, (g)) * vm1);
#define MV4(g, a)                                   \
  {                                                 \
    float k2_ = rlane(kqj2, (g));                   \
    float q2_ = rlane(kqj2, 16 + (g));              \
    float k3_ = rlane(kqj3, (g));                   \
    float q3_ = rlane(kqj3, 16 + (g));              \
    zk2##a = fmaf(k2_, h##g, zk2##a);               \
    zk3##a = fmaf(k3_, h##g, zk3##a);               \
    pv2##a = fmaf(q2_, h##g, pv2##a);               \
    pv3##a = fmaf(q3_, h##g, pv3##a);               \
  }

__global__ __launch_bounds__(256, 1) void k_scan(
    const float* __restrict__ qh, const float* __restrict__ kh, const float* __restrict__ vh,
    const float* __restrict__ av, const float* __restrict__ mv, const int* __restrict__ mask,
    const float* __restrict__ qkd, const float* __restrict__ kvq,
    const float* __restrict__ kkx, const float* __restrict__ vvx, const float* __restrict__ qxx,
    float* __restrict__ y0p, float* __restrict__ y1p, float* __restrict__ y2p,
    float* __restrict__ y3p) {
  int c = blockIdx.x;  // (b*NH+h)*KTS + kt
  int kt = c & 3;
  int bh = c >> 2;
  int b = bh >> 3;
  int h = bh & 7;
  int tid = threadIdx.x;
  int w = tid >> 6;     // wave id: owns d in [16w,16w+16)
  int lane = tid & 63;  // = e
  int dbase = w * 16;

  const float* kp = kh + (size_t)bh * SEQT * HDIM;
  const float* qp = qh + (size_t)bh * SEQT * HDIM;
  const float* vp = vh + (size_t)bh * SEQT * HDIM;
  const float* ap = av + (size_t)c * SEQT;
  const float* mp = mv + (size_t)c * SEQT;
  const float* qkp = qkd + (size_t)bh * SEQT;
  const float* kvp = kvq + (size_t)bh * SEQT;
  const float* kkp = kkx + (size_t)bh * SEQT;
  const float* vvp = vvx + (size_t)bh * SEQT;
  const float* qxp = qxx + (size_t)bh * SEQT;
  const int* mk = mask + (size_t)b * SEQT;
  float* ysel = (kt == 0) ? y0p : (kt == 1) ? y1p : (kt == 2) ? y2p : y3p;
  float* ypo = ysel + (size_t)(b * SEQT) * HIDN + h * HDIM + lane;

  __shared__ __align__(16) float2 Zb[2][4];        // [P][w] = {Z0, Z1} partials
  __shared__ __align__(16) float Pb[2][2][4][64];  // [P][which][w][e]
  __shared__ int cnt;

  G16P(DECLH)  // h0..h15
  float gprev = 1.0f;
  float usq = 0.0f;

  // lanes 0-15: k-slice; lanes 16-31: q-slice; lanes 32-63 duplicate.
  int off = lane & 15;
  const float* kqbase = ((lane >> 4) & 1) ? qp : kp;
  int kqidx = dbase + off;

  // stages j0..j5 = steps s..s+5 (round r starts with s = 2r)
  float kqj0 = kqbase[kqidx];
  float kqj1 = kqbase[(size_t)1 * HDIM + kqidx];
  float kqj2 = kqbase[(size_t)2 * HDIM + kqidx];
  float kqj3 = kqbase[(size_t)3 * HDIM + kqidx];
  float kqj4 = kqbase[(size_t)4 * HDIM + kqidx];
  float kqj5 = kqbase[(size_t)5 * HDIM + kqidx];
  float vj0 = vp[lane], vj1 = vp[HDIM + lane], vj2 = vp[2 * HDIM + lane];
  float vj3 = vp[3 * HDIM + lane], vj4 = vp[4 * HDIM + lane], vj5 = vp[5 * HDIM + lane];
  float a0 = ap[0], a1 = ap[1], a2 = ap[2], a3 = ap[3], a4 = ap[4], a5 = ap[5];
  float mx0 = mp[0], mx1 = mp[1], mx2 = mp[2], mx3 = mp[3], mx4 = mp[4], mx5 = mp[5];
  float m0 = (float)mk[0], m1 = (float)mk[1], m2 = (float)mk[2];
  float m3 = (float)mk[3], m4 = (float)mk[4], m5 = (float)mk[5];
  float qk0 = qkp[0], qk1 = qkp[1], qk2 = qkp[2], qk3 = qkp[3], qk4 = qkp[4], qk5 = qkp[5];
  float kv0 = kvp[0], kv1 = kvp[1], kv2 = kvp[2], kv3 = kvp[3], kv4 = kvp[4], kv5 = kvp[5];
  float kko0 = kkp[1], kko1 = kkp[3], kko2 = kkp[5];
  float vvo0 = vvp[1], vvo1 = vvp[3], vvo2 = vvp[5];
  float qxo0 = qxp[1], qxo1 = qxp[3], qxo2 = qxp[5];

  // zero parity-0 exchange (u_{-1} = 0) and counter
  if (tid == 0) cnt = 0;
  if (lane == 0) Zb[0][w] = make_float2(0.f, 0.f);
  Pb[0][0][w][lane] = 0.f;
  Pb[0][1][w][lane] = 0.f;
  __syncthreads();

  for (int s = 0; s < SEQT; s += 2) {
    int r = s >> 1;
    int P = r & 1;
    int t6 = s + 6, t7 = s + 7;
    if (t6 > SEQT - 1) t6 = SEQT - 1;
    if (t7 > SEQT - 1) t7 = SEQT - 1;
    float kqN6 = kqbase[(size_t)t6 * HDIM + kqidx];
    float kqN7 = kqbase[(size_t)t7 * HDIM + kqidx];
    float vN6 = vp[(size_t)t6 * HDIM + lane];
    float vN7 = vp[(size_t)t7 * HDIM + lane];
    float aN6 = ap[t6], aN7 = ap[t7];
    float mxN6 = mp[t6], mxN7 = mp[t7];
    float mN6 = (float)mk[t6], mN7 = (float)mk[t7];
    float qkN6 = qkp[t6], qkN7 = qkp[t7];
    float kvN6 = kvp[t6], kvN7 = kvp[t7];
    float kkN = kkp[t7], vvN = vvp[t7], qxN = qxp[t7];

    // exchange reads (parity P, written by round r-1, synced)
    float2 zb0 = Zb[P][0], zb1 = Zb[P][1], zb2 = Zb[P][2], zb3 = Zb[P][3];
    float zs = (zb0.x + zb1.x) + (zb2.x + zb3.x);
    float w1 = (zb0.y + zb1.y) + (zb2.y + zb3.y);

    // step s: g via scalar recurrence; h-update needs only gprev
    float ag0 = a0 * gprev;
    float vm0 = m0 * vj0;
    G16P(HUP0)  // h = ag0*h + vm0*k_s[d]
    float usq0 = fmaf(ag0 * ag0, usq, fmaf(2.0f * ag0 * m0, zs, (m0 * m0) * kv0));
    usq0 = fmaxf(usq0, 0.0f);
    float g0 = fminf(16.0f * rsqrtf(usq0), 1.0f);

    // step s+1: corrected z, then g1, then h-update
    float z1 = fmaf(ag0, w1, (m0 * kko0) * vvo0);
    float ag1 = a1 * g0;
    float vm1 = m1 * vj1;
    G16P(HUP1)
    float usq1 = fmaf(ag1 * ag1, usq0, fmaf(2.0f * ag1 * m1, z1, (m1 * m1) * kv1));
    usq1 = fmaxf(usq1, 0.0f);
    float g1 = fminf(16.0f * rsqrtf(usq1), 1.0f);

    // matvecs for steps s+2, s+3 against u_{s+1}
    float zk20 = 0.f, zk21 = 0.f, zk22 = 0.f, zk23 = 0.f;
    float zk30 = 0.f, zk31 = 0.f, zk32 = 0.f, zk33 = 0.f;
    float pv20 = 0.f, pv21 = 0.f, pv22 = 0.f, pv23 = 0.f;
    float pv30 = 0.f, pv31 = 0.f, pv32 = 0.f, pv33 = 0.f;
    G16P(MV4)
    float zk2s = (zk20 + zk21) + (zk22 + zk23);
    float zk3s = (zk30 + zk31) + (zk32 + zk33);
    float Z0n = wsum64_fast(zk2s * vj2);
    float Z1n = wsum64_fast(zk3s * vj3);
    float P0n = (pv20 + pv21) + (pv22 + pv23);
    float P1n = (pv30 + pv31) + (pv32 + pv33);

    // y-stores (read parity P BEFORE the sync increment)
    if (w == 0) {
      float pe = (Pb[P][0][0][lane] + Pb[P][0][1][lane]) +
                 (Pb[P][0][2][lane] + Pb[P][0][3][lane]);
      ypo[(size_t)s * HIDN] = (g0 * mx0) * fmaf(ag0, pe, (m0 * qk0) * vj0);
    } else if (w == 1) {
      float pe = (Pb[P][1][0][lane] + Pb[P][1][1][lane]) +
                 (Pb[P][1][2][lane] + Pb[P][1][3][lane]);
      float p1 = fmaf(ag0, pe, (m0 * qxo0) * vj0);
      ypo[(size_t)(s + 1) * HIDN] = (g1 * mx1) * fmaf(ag1, p1, (m1 * qk1) * vj1);
    }

    // exchange writes (parity P^1) + spin-sync
    if (lane == 0) Zb[P ^ 1][w] = make_float2(Z0n, Z1n);
    Pb[P ^ 1][0][w][lane] = P0n;
    Pb[P ^ 1][1][w][lane] = P1n;
    asm volatile("s_waitcnt lgkmcnt(0)" ::: "memory");
    if (lane == 0) atomicAdd(&cnt, 1);
    {
      int target = 4 * (r + 1);
      while (*(volatile int*)&cnt < target) {
      }
    }
    asm volatile("" ::: "memory");

    gprev = g1;
    usq = usq1;
    kqj0 = kqj2; kqj1 = kqj3; kqj2 = kqj4; kqj3 = kqj5; kqj4 = kqN6; kqj5 = kqN7;
    vj0 = vj2; vj1 = vj3; vj2 = vj4; vj3 = vj5; vj4 = vN6; vj5 = vN7;
    a0 = a2; a1 = a3; a2 = a4; a3 = a5; a4 = aN6; a5 = aN7;
    mx0 = mx2; mx1 = mx3; mx2 = mx4; mx3 = mx5; mx4 = mxN6; mx5 = mxN7;
    m0 = m2; m1 = m3; m2 = m4; m3 = m5; m4 = mN6; m5 = mN7;
    qk0 = qk2; qk1 = qk3; qk2 = qk4; qk3 = qk5; qk4 = qkN6; qk5 = qkN7;
    kv0 = kv2; kv1 = kv3; kv2 = kv4; kv3 = kv5; kv4 = kvN6; kv5 = kvN7;
    kko0 = kko1; kko1 = kko2; kko2 = kkN;
    vvo0 = vvo1; vvo1 = vvo2; vvo2 = vvN;
    qxo0 = qxo1; qxo1 = qxo2; qxo2 = qxN;
  }
}

// ---------------- K5: r = x + (sum_kt y) @ oW^T + ob ----------------
__global__ __launch_bounds__(256) void k_gemm_out(
    const float* __restrict__ y0, const float* __restrict__ y1,
    const float* __restrict__ y2, const float* __restrict__ y3,
    const float* __restrict__ oW, const float* __restrict__ ob,
    const float* __restrict__ x, float* __restrict__ r) {
  __shared__ __align__(16) float As[32][68];
  __shared__ __align__(16) float Bs[32][68];
  int tid = threadIdx.x;
  int m0 = blockIdx.x * 64, n0 = blockIdx.y * 64;
  int tm = tid >> 4, tn = tid & 15;
  float acc[4][4] = {};
  int rr = tid >> 2, cc = (tid & 3) * 8;
  for (int k0 = 0; k0 < HIDN; k0 += 32) {
    size_t aoff = (size_t)(m0 + rr) * HIDN + k0 + cc;
#pragma unroll
    for (int half = 0; half < 2; ++half) {
      size_t sh = aoff + half * 4;
      float4 p0 = *(const float4*)(y0 + sh);
      float4 p1 = *(const float4*)(y1 + sh);
      float4 p2 = *(const float4*)(y2 + sh);
      float4 p3 = *(const float4*)(y3 + sh);
      int cbase = cc + half * 4;
      As[cbase + 0][rr] = p0.x + p1.x + p2.x + p3.x;
      As[cbase + 1][rr] = p0.y + p1.y + p2.y + p3.y;
      As[cbase + 2][rr] = p0.z + p1.z + p2.z + p3.z;
      As[cbase + 3][rr] = p0.w + p1.w + p2.w + p3.w;
    }
    const float* s1 = oW + (size_t)(n0 + rr) * HIDN + k0 + cc;
    float4 b0 = *(const float4*)s1;
    float4 b1 = *(const float4*)(s1 + 4);
    Bs[cc + 0][rr] = b0.x; Bs[cc + 1][rr] = b0.y; Bs[cc + 2][rr] = b0.z; Bs[cc + 3][rr] = b0.w;
    Bs[cc + 4][rr] = b1.x; Bs[cc + 5][rr] = b1.y; Bs[cc + 6][rr] = b1.z; Bs[cc + 7][rr] = b1.w;
    __syncthreads();
#pragma unroll
    for (int kk = 0; kk < 32; ++kk) {
      float4 a4 = *(const float4*)&As[kk][tm * 4];
      float4 b4 = *(const float4*)&Bs[kk][tn * 4];
      float aa[4] = {a4.x, a4.y, a4.z, a4.w};
      float bb[4] = {b4.x, b4.y, b4.z, b4.w};
#pragma unroll
      for (int i = 0; i < 4; ++i)
#pragma unroll
        for (int j = 0; j < 4; ++j) acc[i][j] += aa[i] * bb[j];
    }
    __syncthreads();
  }
#pragma unroll
  for (int i = 0; i < 4; ++i) {
    int mr = m0 + tm * 4 + i;
#pragma unroll
    for (int j = 0; j < 4; ++j) {
      int nc = n0 + tn * 4 + j;
      r[(size_t)mr * HIDN + nc] = x[(size_t)mr * HIDN + nc] + acc[i][j] + ob[nc];
    }
  }
}

// ---------------- K6: LayerNorm -> out ----------------
__global__ __launch_bounds__(256) void k_layernorm(
    const float* __restrict__ r, const float* __restrict__ w, const float* __restrict__ bb,
    float* __restrict__ out) {
  int m = blockIdx.x;
  int tid = threadIdx.x;
  const float* row = r + (size_t)m * HIDN;
  float2 v = *(const float2*)(row + tid * 2);
  float s = wred(v.x + v.y);
  float ss = wred(v.x * v.x + v.y * v.y);
  __shared__ float r1[4], r2[4];
  int lane = tid & 63, wv = tid >> 6;
  if (lane == 0) {
    r1[wv] = s;
    r2[wv] = ss;
  }
  __syncthreads();
  float S = r1[0] + r1[1] + r1[2] + r1[3];
  float SS = r2[0] + r2[1] + r2[2] + r2[3];
  float mu = S * (1.0f / HIDN);
  float var = SS * (1.0f / HIDN) - mu * mu;
  float inv = rsqrtf(var + 1e-5f);
  float2 w2 = *(const float2*)(w + tid * 2);
  float2 b2 = *(const float2*)(bb + tid * 2);
  float2 o;
  o.x = (v.x - mu) * inv * w2.x + b2.x;
  o.y = (v.y - mu) * inv * w2.y + b2.y;
  *(float2*)(out + (size_t)m * HIDN + tid * 2) = o;
}

// ---------------- launch ----------------
extern "C" void kernel_launch(void* const* d_in, const int* in_sizes, int n_in,
                              void* d_out, int out_size, void* d_ws, size_t ws_size,
                              hipStream_t stream) {
  const float* x = (const float*)d_in[0];
  const float* in_w = (const float*)d_in[1];
  const float* qW = (const float*)d_in[2];
  const float* kW = (const float*)d_in[3];
  const float* vW = (const float*)d_in[4];
  const float* aW = (const float*)d_in[5];
  const float* ab = (const float*)d_in[6];
  const float* mW = (const float*)d_in[7];
  const float* mb = (const float*)d_in[8];
  const float* oW = (const float*)d_in[9];
  const float* ob = (const float*)d_in[10];
  const float* kn_w = (const float*)d_in[11];
  const float* vn_w = (const float*)d_in[12];
  const float* ln_w = (const float*)d_in[13];
  const float* ln_b = (const float*)d_in[14];
  const int* mask = (const int*)d_in[15];

  float* ws = (float*)d_ws;
  float* xn = ws + 0;
  float* qb = ws + 1048576;
  float* kb = ws + 2097152;
  float* vb = ws + 3145728;
  float* apre = ws + 4194304;
  float* mpre = ws + 4259840;
  float2* tab = (float2*)(ws + 4325376);
  float* qh = ws + 4390912;
  float* kh = ws + 5439488;
  float* vh = ws + 6488064;
  float* avv = ws + 7536640;
  float* mvv = ws + 7602176;
  float* y3 = ws + 7667712;
  float* y0 = qb;
  float* y1 = kb;
  float* y2 = vb;
  float* rr = xn;
  float* qkd = ws + 0;
  float* kvq = ws + 16384;
  float* kkx = ws + 32768;
  float* vvx = ws + 49152;
  float* qxx = ws + 65536;

  k_rope_table<<<128, 256, 0, stream>>>(tab);
  k_rmsnorm_in<<<NTOK, 256, 0, stream>>>(x, in_w, xn);
  dim3 gBig(32, 8);
  k_gemm_qkv<<<gBig, 256, 0, stream>>>(xn, qW, kW, vW, qb, kb, vb);
  k_gemm_am<<<32, 256, 0, stream>>>(xn, aW, mW, apre, mpre);
  k_postproc<<<4096, 256, 0, stream>>>(qb, kb, vb, apre, mpre, ab, mb, kn_w, vn_w, tab,
                                       qh, kh, vh, avv, mvv, qkd, kvq);
  k_cross<<<4096, 256, 0, stream>>>(qh, kh, vh, kkx, vvx, qxx);
  k_scan<<<64, 256, 0, stream>>>(qh, kh, vh, avv, mvv, mask, qkd, kvq, kkx, vvx, qxx,
                                 y0, y1, y2, y3);
  k_gemm_out<<<gBig, 256, 0, stream>>>(y0, y1, y2, y3, oW, ob, x, rr);
  k_layernorm<<<NTOK, 256, 0, stream>>>(rr, ln_w, ln_b, (float*)d_out);
  (void)in_sizes; (void)n_in; (void)out_size; (void)ws_size;
}